// Round 20
// baseline (591.696 us; speedup 1.0000x reference)
//
#include <hip/hip_runtime.h>
#include <math.h>

#ifndef M_PI
#define M_PI 3.14159265358979323846
#endif

// off2[l] = sum_{l'<l} (2l'+1)^2
__device__ const int c_off2[11] = {0,1,10,35,84,165,286,455,680,969,1330};
// offH[l] = sum_{l'<l} (l'+1)(2l'+1) : half-layout (rows m>=0 only), total 715
__device__ const int c_offH[11] = {0,1,7,22,50,95,161,252,372,525,715};
// T[l] = l(l+1)/2 : compact column base for ns>=0 packing (c = T[l]+ns, ns in [0,l]); total 136
__device__ const int c_T[17] = {0,1,3,6,10,15,21,28,36,45,55,66,78,91,105,120,136};

__device__ __forceinline__ int l_from_sq(int off){ int l=0; while((l+1)*(l+1)<=off) l++; return l; }
__device__ __forceinline__ int l_from_offH(int off){ int l=0; while(c_offH[l+1]<=off) l++; return l; }
__device__ __forceinline__ int l_from_T(int c){ int l=0; while(c_T[l+1]<=c) l++; return l; }

// ---------------- Wigner Delta = d^l(pi/2) via matrix exponential (fp64) ----------------
__global__ void k_delta(double* Dd, float* Df){
  int l = blockIdx.x; int n = 2*l+1; int n2=n*n;
  __shared__ double A[961], T[961], Tm[961];
  for (int idx=threadIdx.x; idx<n2; idx+=1024){
    int r=idx/n, c=idx-r*n;
    double v=0.0;
    if (r==c+1){ double m=(double)(c-l); v = -0.5*sqrt((double)l*(l+1)-m*(m+1)); }
    else if (c==r+1){ double m=(double)(r-l); v = 0.5*sqrt((double)l*(l+1)-m*(m+1)); }
    A[idx] = v*(M_PI*0.5/128.0);
    T[idx] = (r==c)?1.0:0.0;
  }
  __syncthreads();
  for (int j=14; j>=1; --j){
    for (int idx=threadIdx.x; idx<n2; idx+=1024){
      int r=idx/n, c=idx-r*n; double acc=0.0;
      if (r>0)   acc += A[r*n+(r-1)]*T[(r-1)*n+c];
      if (r<n-1) acc += A[r*n+(r+1)]*T[(r+1)*n+c];
      Tm[idx]=acc;
    }
    __syncthreads();
    for (int idx=threadIdx.x; idx<n2; idx+=1024){
      int r=idx/n, c=idx-r*n;
      T[idx] = ((r==c)?1.0:0.0) + Tm[idx]/(double)j;
    }
    __syncthreads();
  }
  for (int s=0; s<7; ++s){
    for (int idx=threadIdx.x; idx<n2; idx+=1024){
      int r=idx/n, c=idx-r*n; double acc=0.0;
      for (int q=0;q<n;q++) acc += T[r*n+q]*T[q*n+c];
      Tm[idx]=acc;
    }
    __syncthreads();
    for (int idx=threadIdx.x; idx<n2; idx+=1024) T[idx]=Tm[idx];
    __syncthreads();
  }
  for (int idx=threadIdx.x; idx<n2; idx+=1024){ Dd[l*961+idx]=T[idx]; Df[l*961+idx]=(float)T[idx]; }
}

// ---------------- quadrature weights + phase tables ----------------
__global__ void k_qw(float* qw30, float* qw16, float* qw10, float2* ph32, float2* ph20, float2* ph60){
  int t=threadIdx.x;
  if (t<60){
    double beta=M_PI*(2*t+1)/120.0, s=0.0;
    for (int j=0;j<30;j++) s += sin((double)(2*t+1)*(2*j+1)*M_PI/120.0)/(double)(2*j+1);
    qw30[t]=(float)((2.0/30.0)*sin(beta)*s);
    double a=2.0*M_PI*t/60.0; ph60[t]=make_float2((float)cos(a),(float)sin(a));
  }
  if (t<32){
    double beta=M_PI*(2*t+1)/64.0, s=0.0;
    for (int j=0;j<16;j++) s += sin((double)(2*t+1)*(2*j+1)*M_PI/64.0)/(double)(2*j+1);
    qw16[t]=(float)((2.0/16.0)*sin(beta)*s);
    double a=2.0*M_PI*t/32.0; ph32[t]=make_float2((float)cos(a),(float)sin(a));
  }
  if (t<20){
    double beta=M_PI*(2*t+1)/40.0, s=0.0;
    for (int j=0;j<10;j++) s += sin((double)(2*t+1)*(2*j+1)*M_PI/40.0)/(double)(2*j+1);
    qw10[t]=(float)((2.0/10.0)*sin(beta)*s);
    double a=2.0*M_PI*t/20.0; ph20[t]=make_float2((float)cos(a),(float)sin(a));
  }
}

// ---------------- beta-grid Wigner tables from Delta ----------------
__global__ void k_tables(const double* Dd, const float* qw30, const float* qw16, const float* qw10,
                         float* wd_s2, float* dif16, float* wd16, float* dif10){
  int bid=blockIdx.x;
  __shared__ double cc[32], ss[32];
  int l,k,mode; double beta;
  if (bid<960){ mode=0; l=bid/60; k=bid%60; beta=M_PI*(2*k+1)/120.0; }
  else if (bid<1472){ mode=1; int q=bid-960; l=q/32; k=q%32; beta=M_PI*(2*k+1)/64.0; }
  else { mode=2; int q=bid-1472; l=q/20; k=q%20; beta=M_PI*(2*k+1)/40.0; }
  int n=2*l+1;
  for (int kk=threadIdx.x; kk<=l; kk+=256){ cc[kk]=cos(kk*beta); ss[kk]=sin(kk*beta); }
  __syncthreads();
  const double* D = Dd + l*961;
  if (mode==0){
    for (int mm=threadIdx.x; mm<n; mm+=256){
      int m=mm-l; int p=((m)%4+4)%4; double s=0.0;
      for (int kk=-l; kk<=l; ++kk){
        int ak = kk<0?-kk:kk;
        double c=cc[ak], sn=(kk<0)?-ss[ak]:ss[ak];
        double f=(p==0)?c:(p==1)?sn:(p==2)?-c:-sn;
        s += D[(kk+l)*n+mm]*D[(kk+l)*n+l]*f;
      }
      wd_s2[(l*60+k)*31+mm] = (float)(s*(double)qw30[k]*(2.0*M_PI/60.0));
    }
  } else if (mode==1){
    for (int idx=threadIdx.x; idx<n*n; idx+=256){
      int mm=idx/n, nn=idx-mm*n; int m=mm-l, nb=nn-l;
      int p=((m-nb)%4+4)%4; double s=0.0;
      for (int kk=-l; kk<=l; ++kk){
        int ak = kk<0?-kk:kk;
        double c=cc[ak], sn=(kk<0)?-ss[ak]:ss[ak];
        double f=(p==0)?c:(p==1)?sn:(p==2)?-c:-sn;
        s += D[(kk+l)*n+mm]*D[(kk+l)*n+nn]*f;
      }
      dif16[(size_t)(l*32+k)*961+idx] = (float)((2*l+1)*s);
      if (l<10) wd16[(size_t)(l*32+k)*361+idx] = (float)(s*(double)qw16[k]*(2.0*M_PI/32.0)*(2.0*M_PI/32.0));
    }
  } else {
    for (int idx=threadIdx.x; idx<n*n; idx+=256){
      int mm=idx/n, nn=idx-mm*n; int m=mm-l, nb=nn-l;
      int p=((m-nb)%4+4)%4; double s=0.0;
      for (int kk=-l; kk<=l; ++kk){
        int ak = kk<0?-kk:kk;
        double c=cc[ak], sn=(kk<0)?-ss[ak]:ss[ak];
        double f=(p==0)?c:(p==1)?sn:(p==2)?-c:-sn;
        s += D[(kk+l)*n+mm]*D[(kk+l)*n+nn]*f;
      }
      dif10[(size_t)(l*20+k)*361+idx] = (float)((2*l+1)*s);
    }
  }
}

// ---------------- project point cloud to S2 grid (max-scatter) ----------------
__global__ void k_project(const float* x, float* img){
  int tid = blockIdx.x*256+threadIdx.x;
  if (tid>=8192) return;
  int b=tid>>10, n=tid&1023;
  float px=x[(b*3+0)*1024+n], py=x[(b*3+1)*1024+n], pz=x[(b*3+2)*1024+n];
  float r = sqrtf(px*px+py*py+pz*pz);
  float rc = fmaxf(r, 1e-8f);
  float ct = fminf(1.f, fmaxf(-1.f, pz/rc));
  float beta = acosf(ct);
  float alpha = atan2f(py, px);
  const float TWO_PI = 6.283185307179586f;
  alpha = fmodf(alpha, TWO_PI); if (alpha<0.f) alpha += TWO_PI;
  int bi = (int)(beta/3.14159265358979323846f*60.f); bi = min(59, max(0, bi));
  int ai = (int)(alpha/TWO_PI*60.f);                 ai = min(59, max(0, ai));
  atomicMax((int*)&img[(b*60+bi)*60+ai], __float_as_int(r));
}

// ---------------- S2 FFT stage a: alpha-DFT per (b,k) -> Gg[b,k,16] ----------------
__global__ void k_s2a(const float* __restrict__ img, const float2* __restrict__ ph60, float2* __restrict__ Gg){
  int bid=blockIdx.x; int b=bid/60, k=bid-60*b;
  __shared__ float im[60];
  int t=threadIdx.x;
  if (t<60) im[t]=img[(b*60+k)*60+t];
  __syncthreads();
  if (t<16){
    float sr=0.f, si=0.f;
    for (int a=0;a<60;a++){ float v=im[a]; float2 p=ph60[(t*a)%60]; sr+=v*p.x; si-=v*p.y; }
    Gg[(b*60+k)*16+t]=make_float2(sr,si);
  }
}

// ---------------- S2 FFT stage b (split 32 blocks): Gg -> X[b, l^2+mm] ----------------
__global__ void k_s2b(const float2* __restrict__ Gg, const float* __restrict__ wd_s2, float2* __restrict__ X){
  int b=blockIdx.x>>2; int quarter=blockIdx.x&3;
  __shared__ float2 G[960];
  for (int i=threadIdx.x;i<960;i+=64) G[i]=Gg[b*960+i];
  __syncthreads();
  int off=quarter*64 + threadIdx.x;
  int l=0; while((l+1)*(l+1)<=off) l++;
  int mm=off-l*l; int m=mm-l; int am = m<0?-m:m;
  float xr=0.f, xi=0.f;
  for (int k=0;k<60;k++){
    float w=wd_s2[(l*60+k)*31+mm];
    float2 g=G[(k<<4)+am];
    float gi = (m<0)? -g.y : g.y;
    xr += w*g.x; xi += w*gi;
  }
  X[b*256+off]=make_float2(xr,xi);
}

// ---------------- S2 RFT: w_s2 -> YC[f*256+off] = conj(Y^l[f,mm]) ----------------
__global__ void k_yc(const float* w_s2, const float* Df, const float2* ph60, float2* YC){
  int f=blockIdx.x; int t=threadIdx.x; // 64 threads
  __shared__ float wv[60];
  __shared__ float2 W[16];
  for (int p=t;p<60;p+=64) wv[p]=w_s2[f*60+p];
  __syncthreads();
  if (t<16){
    float sr=0.f, si=0.f;
    for (int p=0;p<60;p++){ float2 ph=ph60[(t*p)%60]; sr+=wv[p]*ph.x; si-=wv[p]*ph.y; }
    W[t]=make_float2(sr/60.f, si/60.f);
  }
  __syncthreads();
  for (int off=t; off<256; off+=64){
    int l=0; while((l+1)*(l+1)<=off) l++;
    int mm=off-l*l; int m=mm-l; int am=m<0?-m:m;
    float dh=Df[l*961 + mm*(2*l+1) + l];
    float2 wm=W[am];
    float wi = (m>=0)? -wm.y : wm.y;   // conj(What[m_signed])
    YC[f*256+off]=make_float2(dh*wm.x, dh*wi);
  }
}

// ---------------- u compact (ns>=0), load-balanced: l>=8 blocks split ns-range ----------------
__global__ void k_u(const float2* X, const float* dif16, const float2* ph32g, float2* u){
  int bid=blockIdx.x;
  int l, k, ns0, ns1;
  if (bid < 256){ l = bid>>5; k = bid&31; ns0=0; ns1=l+1; }
  else {
    int q=bid-256; l = 8 + (q>>6); int half=(q>>5)&1; k=q&31;
    int mid=(l+2)>>1;  // ceil((l+1)/2)
    ns0 = half? mid : 0; ns1 = half? (l+1) : mid;
  }
  int n=2*l+1;
  __shared__ float d[961];
  __shared__ float2 Xs[8][31];
  __shared__ float2 ph[32];
  int t=threadIdx.x;
  if (t<32) ph[t]=ph32g[t];
  for (int i=t;i<n*n;i+=256) d[i]=dif16[(size_t)(l*32+k)*961+i];
  if (t<8*n){ int b=t/n, mm=t-b*n; Xs[b][mm]=X[b*256+l*l+mm]; }
  __syncthreads();
  int b=t>>5, a=t&31;
  int base=((b*32+k)*32+a)*136 + c_T[l];
  for (int ns=ns0; ns<ns1; ++ns){
    float ar=0.f, ai=0.f;
    int nn = ns + l;
    for (int mm=0; mm<n; ++mm){
      float2 x=Xs[b][mm];
      float2 p=ph[((mm-l)*a)&31];
      float pr=x.x*p.x-x.y*p.y, pi=x.x*p.y+x.y*p.x;
      float dv=d[mm*n+nn];
      ar += dv*pr; ai += dv*pi;
    }
    u[base+ns]=make_float2(ar,ai);
  }
}

// ---------------- big inverse transform v4 (R12-proven): R7 GEMM + transposed-h coalesced store + fused BN
// h stored TRANSPOSED: h[bc][k][g*32+a]. k_g is the only consumer.
#define KH_F 8
__global__ __launch_bounds__(256) void k_h(const float2* __restrict__ u, const float2* __restrict__ YC,
                                           const float2* __restrict__ ph32g, float* __restrict__ h,
                                           double2* __restrict__ part){
  int bid=blockIdx.x;
  int fg = bid % 13; int rem = bid/13; int k = rem & 31; int b = rem >> 5;
  int f0 = fg*KH_F; int F_act = (f0+KH_F<=100)? KH_F : (100-f0);

  __shared__ float usr[136*33], usi[136*33];   // [c][a] pad 33
  __shared__ float2 ysc[KH_F*136];             // [fi][c]
  __shared__ float vr[KH_F*32*17], vi[KH_F*32*17]; // [fi][a][ns] pad 17
  __shared__ float2 ph[32];
  int t=threadIdx.x;
  if (t<32) ph[t]=ph32g[t];

  // stage A: load u transposed [c][a], Y compact
  {
    const float2* ub = u + (size_t)((b*32+k)*32)*136;
    for (int i=t; i<32*136; i+=256){
      int a=i/136, c=i-a*136;
      float2 U=ub[i];
      usr[c*33+a]=U.x; usi[c*33+a]=U.y;
    }
  }
  for (int i=t; i<KH_F*136; i+=256){
    int fi=i/136, c=i-fi*136;
    float2 y=make_float2(0.f,0.f);
    if (fi<F_act){
      int l=l_from_T(c); int ns=c-c_T[l];
      y=YC[(size_t)(f0+fi)*256 + l*l+l+ns];
    }
    ysc[i]=y;
  }
  __syncthreads();

  // stage B: register-tiled GEMM, 256 jobs = ns(16) x ftile(2) x atile(8); acc 4f x 4a complex
  {
    int ns = t>>4; int sub = t&15; int ft = sub>>3; int at = sub&7;
    int a0 = at*4;
    float ar[16], ai[16];
    #pragma unroll
    for (int q=0;q<16;q++){ ar[q]=0.f; ai[q]=0.f; }
    for (int l=ns; l<16; ++l){
      int c = c_T[l]+ns;
      float2 y0=ysc[(ft*4+0)*136+c];
      float2 y1=ysc[(ft*4+1)*136+c];
      float2 y2=ysc[(ft*4+2)*136+c];
      float2 y3=ysc[(ft*4+3)*136+c];
      float ur0=usr[c*33+a0+0], ur1=usr[c*33+a0+1], ur2=usr[c*33+a0+2], ur3=usr[c*33+a0+3];
      float ui0=usi[c*33+a0+0], ui1=usi[c*33+a0+1], ui2=usi[c*33+a0+2], ui3=usi[c*33+a0+3];
      #define CM(j,Y,i_,URi,UIi) \
        ar[(j)*4+(i_)] += (Y).x*URi - (Y).y*UIi; \
        ai[(j)*4+(i_)] += (Y).x*UIi + (Y).y*URi;
      CM(0,y0,0,ur0,ui0) CM(0,y0,1,ur1,ui1) CM(0,y0,2,ur2,ui2) CM(0,y0,3,ur3,ui3)
      CM(1,y1,0,ur0,ui0) CM(1,y1,1,ur1,ui1) CM(1,y1,2,ur2,ui2) CM(1,y1,3,ur3,ui3)
      CM(2,y2,0,ur0,ui0) CM(2,y2,1,ur1,ui1) CM(2,y2,2,ur2,ui2) CM(2,y2,3,ur3,ui3)
      CM(3,y3,0,ur0,ui0) CM(3,y3,1,ur1,ui1) CM(3,y3,2,ur2,ui2) CM(3,y3,3,ur3,ui3)
      #undef CM
    }
    #pragma unroll
    for (int j=0;j<4;j++){
      #pragma unroll
      for (int i=0;i<4;i++){
        int fi=ft*4+j, a=a0+i;
        vr[(fi*32+a)*17+ns]=ar[j*4+i];
        vi[(fi*32+a)*17+ns]=ai[j*4+i];
      }
    }
  }
  __syncthreads();

  // stage C: gamma-DFT (g-fold) -> direct transposed coalesced store; fused BN partials
  {
    int fi=t>>5, a=t&31;
    float xr[16], xi[16];
    #pragma unroll
    for (int ns=0;ns<16;ns++){ xr[ns]=vr[(fi*32+a)*17+ns]; xi[ns]=vi[(fi*32+a)*17+ns]; }
    float vr0 = xr[0];
    bool wr = (fi<F_act);
    float* hp = h + ((size_t)(b*100+f0+fi)*32 + k)*1024 + a;
    double s=0.0, q=0.0;
    #pragma unroll
    for (int g=0; g<16; ++g){
      float se=0.f, so=0.f;
      #pragma unroll
      for (int ns=0; ns<16; ++ns){
        float2 p=ph[(ns*g)&31];
        float term = xr[ns]*p.x - xi[ns]*p.y;
        if (ns & 1) so += term; else se += term;
      }
      float hg  = 2.f*(se+so) - vr0;
      float hg16= 2.f*(se-so) - vr0;
      if (wr){ hp[g*32]=hg; hp[(g+16)*32]=hg16; }
      double d1=(double)hg, d2=(double)hg16;
      s += d1+d2; q += d1*d1+d2*d2;
    }
    for (int d=16; d>0; d>>=1){ s += __shfl_down(s, d, 32); q += __shfl_down(q, d, 32); }
    if (a==0 && fi<F_act){
      atomicAdd(&part[b*100+f0+fi].x, s);
      atomicAdd(&part[b*100+f0+fi].y, q);
    }
  }
}

// ---------------- BN stage 2 (fold partials -> scale/shift) ----------------
__global__ void k_bn2(const double2* __restrict__ partial, int per, const float* g, const float* bb,
                      float* scale, float* shift){
  int f=blockIdx.x*64+threadIdx.x;
  if (f>=100) return;
  double s=0.0, q=0.0;
  for (int b=0;b<8;b++){ double2 v=partial[b*100+f]; s+=v.x; q+=v.y; }
  double cnt=8.0*(double)per;
  double mu=s/cnt, var=q/cnt-mu*mu;
  double sc=(double)g[f]/sqrt(var+1e-5);
  scale[f]=(float)sc; shift[f]=(float)((double)bb[f]-mu*sc);
}

// ---------------- k_g: per (b,c,k): BN+ReLU + alpha-DFT + gamma-DFT -> G[bc,k,190]
// h is TRANSPOSED [g*32+a]; LDS y padded [g*33+a].
__global__ __launch_bounds__(64) void k_g(const float* __restrict__ h, const float* __restrict__ scale,
                                          const float* __restrict__ shift, const float2* __restrict__ ph32g,
                                          float2* __restrict__ G){
  int bid=blockIdx.x; int k=bid&31; int bc=bid>>5; int c=bc%100;
  __shared__ float y[32*33];
  __shared__ float tsr[10*33], tsi[10*33];
  __shared__ float2 ph[32];
  int t=threadIdx.x;
  if (t<32) ph[t]=ph32g[t];
  float sc=scale[c], sh=shift[c];
  const float* hb = h + (size_t)bc*32768 + k*1024;
  for (int i=t;i<1024;i+=64){ int g=i>>5, a=i&31; y[g*33+a]=fmaxf(hb[i]*sc+sh, 0.f); }
  __syncthreads();
  for (int i=t;i<320;i+=64){
    int m=i>>5, g=i&31;
    float sr=0.f, si=0.f;
    for (int a=0;a<32;a++){ float v=y[g*33+a]; float2 p=ph[(m*a)&31]; sr+=v*p.x; si-=v*p.y; }
    tsr[m*33+g]=sr; tsi[m*33+g]=si;
  }
  __syncthreads();
  float2* Gp = G + (size_t)(bc*32+k)*190;
  for (int i=t;i<190;i+=64){
    int m=i/19, n9=i-m*19; int ns=n9-9;
    float gr=0.f, gi=0.f;
    for (int g=0;g<32;g++){
      float tr=tsr[m*33+g], ti=tsi[m*33+g];
      float2 p=ph[(ns*g)&31];
      gr += tr*p.x + ti*p.y;
      gi += ti*p.x - tr*p.y;
    }
    Gp[i]=make_float2(gr,gi);
  }
}

// ---------------- k_x2 (half rows m>=0): X2h[bc, offH(l)+m*n+kk] = sum_k wd16[l,k,(m+l)*n+kk] * G[bc,k,j]
__global__ void k_x2(const float2* __restrict__ G, const float* __restrict__ wd16, float2* __restrict__ X2){
  int tid=blockIdx.x*256+threadIdx.x;
  if (tid>=800*715) return;
  int bc=tid/715, i=tid-bc*715;
  int l=l_from_offH(i); int rem=i-c_offH[l]; int n=2*l+1;
  int m=rem/n, kk2=rem-m*n; int ng=kk2-l;   // m>=0 always
  int j = m*19+(ng+9);
  const float2* Gp = G + (size_t)bc*32*190 + j;
  const float*  wp = wd16 + (size_t)l*32*361 + (m+l)*n + kk2;
  float ar=0.f, ai=0.f;
  #pragma unroll 4
  for (int k=0;k<32;k++){
    float2 gv=Gp[(size_t)k*190];
    float  wv=wp[(size_t)k*361];
    ar += wv*gv.x; ai += wv*gv.y;
  }
  X2[tid]=make_float2(ar, ai);
}

// ---------------- What2[m,i,o] ----------------
__global__ void k_wh2(const float* w_so3, const float2* ph32g, float2* WH2){
  int tid=blockIdx.x*256+threadIdx.x;
  if (tid>=10000) return;
  int i=tid/100, o=tid-i*100;
  float wv[32];
  for (int p=0;p<32;p++) wv[p]=w_so3[(i*100+o)*32+p];
  for (int m=0;m<10;m++){
    float sr=0.f, si=0.f;
    for (int p=0;p<32;p++){ float2 ph=ph32g[(m*p)&31]; sr+=wv[p]*ph.x; si-=wv[p]*ph.y; }
    WH2[((size_t)m*100+i)*100+o]=make_float2(sr/32.f, si/32.f);
  }
}

// ---------------- A (half rows): A[bi, offH(l)+m*n+nn] = sum_kk X2h[bi, row m][kk] * Delta^l[nn,kk]
__global__ void k_A(const float2* __restrict__ X2, const float* __restrict__ Df, float2* __restrict__ A){
  int tid = blockIdx.x*256 + threadIdx.x;
  if (tid >= 800*715) return;
  int bi = tid/715, off = tid - bi*715;
  int l = l_from_offH(off); int rem = off - c_offH[l]; int n = 2*l+1;
  int m = rem/n, nn = rem - m*n;
  const float2* Xp = X2 + (size_t)bi*715 + c_offH[l] + m*n;
  const float* Dp = Df + l*961 + nn*n;
  float ar=0.f, ai=0.f;
  for (int kk=0; kk<n; ++kk){
    float2 x = Xp[kk]; float dv = Dp[kk];
    ar += x.x*dv; ai += x.y*dv;
  }
  A[tid] = make_float2(ar, ai);
}

// ---------------- Z2 (half rows): Z2h[b,o, offH(l)+m*n+nn] = sum_i A[b,i, m,nn] * conj(What2[i,o,nsig])
__global__ void k_z2(const float2* A, const float2* WH2, float2* Z2){
  int bid=blockIdx.x; int b=bid&7; int r=bid>>3;
  int l=l_from_sq(r); int nn=r-l*l; int n=2*l+1; int ns=nn-l;
  int nrow=l+1;
  __shared__ float2 As[100*10];
  int t=threadIdx.x;
  for (int idx=t; idx<100*nrow; idx+=256){
    int i=idx/nrow, m=idx-i*nrow;
    As[idx]=A[(size_t)(b*100+i)*715 + c_offH[l] + m*n + nn];
  }
  __syncthreads();
  int mabs = ns<0?-ns:ns;
  const float2* Wp = WH2 + (size_t)mabs*10000;
  float sgn = (ns>=0)? -1.f : 1.f;
  for (int idx=t; idx<100*nrow; idx+=256){
    int o=idx/nrow, m=idx-o*nrow;
    float zr=0.f, zi=0.f;
    for (int i=0;i<100;i++){
      float2 a=As[i*nrow+m];
      float2 w=Wp[i*100+o]; float wr=w.x, wi=sgn*w.y;
      zr += a.x*wr - a.y*wi;
      zi += a.x*wi + a.y*wr;
    }
    Z2[(size_t)(b*100+o)*715 + c_offH[l] + m*n + nn]=make_float2(zr,zi);
  }
}

// ---------------- fused SO3 IFFT at b=10 v3: Hermitian half + fused BN partials for h2 ----------------
__global__ __launch_bounds__(128) void k_ifft10(const float2* __restrict__ Z2, const float* __restrict__ dif10,
                                                const float2* __restrict__ ph20g, float* __restrict__ h2,
                                                double2* __restrict__ part){
  int bid=blockIdx.x; int bf=bid/20, k=bid-20*bf;
  __shared__ float2 M[190];    // [ms 0..9][n9 0..18]
  __shared__ float2 T[200];    // [ms 0..9][g 0..19]
  __shared__ float2 ph[20];
  __shared__ double rs[128], rq[128];
  int t=threadIdx.x;
  if (t<20) ph[t]=ph20g[t];
  const float2* Zp = Z2 + (size_t)bf*715;
  __syncthreads();
  for (int i=t;i<190;i+=128){
    int ms=i/19, n9=i-ms*19; int nsg=n9-9;
    int a2=nsg<0?-nsg:nsg; int l0 = ms>a2?ms:a2;
    float mr=0.f, mi=0.f;
    for (int l=l0;l<10;l++){
      int n=2*l+1;
      float dv=dif10[(size_t)(l*20+k)*361 + (ms+l)*n+(nsg+l)];
      float2 z=Zp[c_offH[l] + ms*n + (nsg+l)];
      mr += dv*z.x; mi += dv*z.y;
    }
    M[i]=make_float2(mr,mi);
  }
  __syncthreads();
  for (int i=t;i<200;i+=128){
    int ms=i/20, g=i-20*ms;
    const float2* Mp=M+ms*19;
    int idx=(11*g)%20;
    float tr=0.f, ti=0.f;
    #pragma unroll
    for (int n9=0;n9<19;n9++){
      float2 mv=Mp[n9]; float2 p=ph[idx];
      tr += mv.x*p.x - mv.y*p.y;
      ti += mv.x*p.y + mv.y*p.x;
      idx += g; if (idx>=20) idx-=20;
    }
    T[i]=make_float2(tr,ti);
  }
  __syncthreads();
  float* hp = h2 + (size_t)bf*8000 + k*400;
  double s=0.0, q=0.0;
  for (int i=t;i<400;i+=128){
    int a=i/20, g=i-20*a;
    float acc = T[g].x;
    int cur=a;
    #pragma unroll
    for (int ms=1; ms<10; ++ms){
      float2 tv=T[ms*20+g]; float2 p=ph[cur];
      acc += 2.f*(tv.x*p.x - tv.y*p.y);
      cur += a; if (cur>=20) cur-=20;
    }
    hp[i]=acc;
    double d=(double)acc; s+=d; q+=d*d;
  }
  rs[t]=s; rq[t]=q; __syncthreads();
  for (int w=64;w>0;w>>=1){ if(t<w){rs[t]+=rs[t+w]; rq[t]+=rq[t+w];} __syncthreads(); }
  if (t==0){
    atomicAdd(&part[bf].x, rs[0]);
    atomicAdd(&part[bf].y, rq[0]);
  }
}

// ---------------- BN2+ReLU + SO3 integrate -> feat ----------------
__global__ void k_integrate(const float* h2, const float* scale, const float* shift, const float* qw10, float* feat){
  int bf=blockIdx.x; int f=bf%100; int t=threadIdx.x;
  float sc=scale[f], sh=shift[f];
  const float* p=h2+(size_t)bf*8000;
  float s=0.f;
  for (int i=t;i<8000;i+=256){
    float v=fmaxf(p[i]*sc+sh, 0.f);
    s += v*qw10[i/400];
  }
  __shared__ float r[256];
  r[t]=s; __syncthreads();
  for (int w=128;w>0;w>>=1){ if(t<w) r[t]+=r[t+w]; __syncthreads(); }
  if (t==0){
    float c=(float)((2.0*M_PI/20.0)*(2.0*M_PI/20.0));
    feat[bf]=r[0]*c;
  }
}

// ---------------- final linear ----------------
__global__ void k_logits(const float* feat, const float* lw, const float* lb, float* out){
  int t=blockIdx.x*64+threadIdx.x;
  if (t>=320) return;
  int b=t/40, c=t-40*b;
  float s=lb[c];
  for (int f=0;f<100;f++) s += feat[b*100+f]*lw[f*40+c];
  out[t]=s;
}

extern "C" void kernel_launch(void* const* d_in, const int* in_sizes, int n_in,
                              void* d_out, int out_size, void* d_ws, size_t ws_size,
                              hipStream_t stream){
  (void)in_sizes; (void)n_in; (void)out_size; (void)ws_size;
  const float* x    = (const float*)d_in[0];
  const float* w_s2 = (const float*)d_in[1];
  const float* bn1g = (const float*)d_in[3];
  const float* bn1b = (const float*)d_in[4];
  const float* w_so3= (const float*)d_in[5];
  const float* bn2g = (const float*)d_in[7];
  const float* bn2b = (const float*)d_in[8];
  const float* linw = (const float*)d_in[9];
  const float* linb = (const float*)d_in[10];
  float* out = (float*)d_out;

  char* base=(char*)d_ws; size_t off=0;
  auto alloc=[&](size_t bytes)->void*{ void* p=base+off; off=(off+bytes+255)&~(size_t)255; return p; };
  double* Dd   = (double*)alloc((size_t)16*961*8);
  float*  Df   = (float*) alloc((size_t)16*961*4);
  float*  qw30 = (float*) alloc(256);
  float*  qw16 = (float*) alloc(256);
  float*  qw10 = (float*) alloc(256);
  float2* ph60 = (float2*)alloc(512);
  float2* ph32 = (float2*)alloc(256);
  float2* ph20 = (float2*)alloc(256);
  float*  wd_s2= (float*) alloc((size_t)16*60*31*4);
  float*  dif16= (float*) alloc((size_t)16*32*961*4);
  float*  wd16 = (float*) alloc((size_t)10*32*361*4);
  float*  dif10= (float*) alloc((size_t)10*20*361*4);
  float*  img  = (float*) alloc((size_t)8*3600*4);
  float2* Gg   = (float2*)alloc((size_t)8*960*8);
  float2* X    = (float2*)alloc((size_t)8*256*8);
  float2* YC   = (float2*)alloc((size_t)100*256*8);
  float2* u    = (float2*)alloc((size_t)8*32*32*136*8);
  float*  h    = (float*) alloc((size_t)8*100*32768*4);
  float*  sc1  = (float*) alloc(512);
  float*  sh1  = (float*) alloc(512);
  float2* Gbuf = (float2*)alloc((size_t)800*32*190*8);
  float2* X2   = (float2*)alloc((size_t)800*715*8);
  float2* WH2  = (float2*)alloc((size_t)10*100*100*8);
  float2* A    = (float2*)alloc((size_t)800*715*8);
  float2* Z2   = (float2*)alloc((size_t)800*715*8);
  float*  h2   = (float*) alloc((size_t)8*100*8000*4);
  float*  sc2  = (float*) alloc(512);
  float*  sh2  = (float*) alloc(512);
  float*  feat = (float*) alloc(4096);
  double2* part= (double2*)alloc((size_t)800*16);

  k_delta<<<16, 1024, 0, stream>>>(Dd, Df);
  k_qw<<<1, 64, 0, stream>>>(qw30, qw16, qw10, ph32, ph20, ph60);
  k_tables<<<1672, 256, 0, stream>>>(Dd, qw30, qw16, qw10, wd_s2, dif16, wd16, dif10);
  hipMemsetAsync(img, 0, (size_t)8*3600*4, stream);
  hipMemsetAsync(part, 0, (size_t)800*16, stream);
  k_project<<<32, 256, 0, stream>>>(x, img);
  k_s2a<<<480, 64, 0, stream>>>(img, ph60, Gg);
  k_s2b<<<32, 64, 0, stream>>>(Gg, wd_s2, X);
  k_yc<<<100, 64, 0, stream>>>(w_s2, Df, ph60, YC);
  k_u<<<768, 256, 0, stream>>>(X, dif16, ph32, u);
  k_h<<<8*32*13, 256, 0, stream>>>(u, YC, ph32, h, part);
  k_bn2<<<2, 64, 0, stream>>>(part, 32768, bn1g, bn1b, sc1, sh1);
  k_g<<<800*32, 64, 0, stream>>>(h, sc1, sh1, ph32, Gbuf);
  k_x2<<<(800*715+255)/256, 256, 0, stream>>>(Gbuf, wd16, X2);
  k_wh2<<<40, 256, 0, stream>>>(w_so3, ph32, WH2);
  k_A<<<(800*715+255)/256, 256, 0, stream>>>(X2, Df, A);
  k_z2<<<800, 256, 0, stream>>>(A, WH2, Z2);
  hipMemsetAsync(part, 0, (size_t)800*16, stream);   // re-zero for h2 BN partials
  k_ifft10<<<16000, 128, 0, stream>>>(Z2, dif10, ph20, h2, part);
  k_bn2<<<2, 64, 0, stream>>>(part, 8000, bn2g, bn2b, sc2, sh2);
  k_integrate<<<800, 256, 0, stream>>>(h2, sc2, sh2, qw10, feat);
  k_logits<<<5, 64, 0, stream>>>(feat, linw, linb, out);
}

// Round 21
// 571.177 us; speedup vs baseline: 1.0359x; 1.0359x over previous
//
#include <hip/hip_runtime.h>
#include <math.h>

#ifndef M_PI
#define M_PI 3.14159265358979323846
#endif

// off2[l] = sum_{l'<l} (2l'+1)^2
__device__ const int c_off2[11] = {0,1,10,35,84,165,286,455,680,969,1330};
// offH[l] = sum_{l'<l} (l'+1)(2l'+1) : half-layout (rows m>=0 only), total 715
__device__ const int c_offH[11] = {0,1,7,22,50,95,161,252,372,525,715};
// T[l] = l(l+1)/2 : compact column base for ns>=0 packing (c = T[l]+ns, ns in [0,l]); total 136
__device__ const int c_T[17] = {0,1,3,6,10,15,21,28,36,45,55,66,78,91,105,120,136};

__device__ __forceinline__ int l_from_sq(int off){ int l=0; while((l+1)*(l+1)<=off) l++; return l; }
__device__ __forceinline__ int l_from_offH(int off){ int l=0; while(c_offH[l+1]<=off) l++; return l; }
__device__ __forceinline__ int l_from_T(int c){ int l=0; while(c_T[l+1]<=c) l++; return l; }

// ---------------- Wigner Delta = d^l(pi/2) via matrix exponential (fp64) ----------------
__global__ void k_delta(double* Dd, float* Df){
  int l = blockIdx.x; int n = 2*l+1; int n2=n*n;
  __shared__ double A[961], T[961], Tm[961];
  for (int idx=threadIdx.x; idx<n2; idx+=1024){
    int r=idx/n, c=idx-r*n;
    double v=0.0;
    if (r==c+1){ double m=(double)(c-l); v = -0.5*sqrt((double)l*(l+1)-m*(m+1)); }
    else if (c==r+1){ double m=(double)(r-l); v = 0.5*sqrt((double)l*(l+1)-m*(m+1)); }
    A[idx] = v*(M_PI*0.5/128.0);
    T[idx] = (r==c)?1.0:0.0;
  }
  __syncthreads();
  for (int j=14; j>=1; --j){
    for (int idx=threadIdx.x; idx<n2; idx+=1024){
      int r=idx/n, c=idx-r*n; double acc=0.0;
      if (r>0)   acc += A[r*n+(r-1)]*T[(r-1)*n+c];
      if (r<n-1) acc += A[r*n+(r+1)]*T[(r+1)*n+c];
      Tm[idx]=acc;
    }
    __syncthreads();
    for (int idx=threadIdx.x; idx<n2; idx+=1024){
      int r=idx/n, c=idx-r*n;
      T[idx] = ((r==c)?1.0:0.0) + Tm[idx]/(double)j;
    }
    __syncthreads();
  }
  for (int s=0; s<7; ++s){
    for (int idx=threadIdx.x; idx<n2; idx+=1024){
      int r=idx/n, c=idx-r*n; double acc=0.0;
      for (int q=0;q<n;q++) acc += T[r*n+q]*T[q*n+c];
      Tm[idx]=acc;
    }
    __syncthreads();
    for (int idx=threadIdx.x; idx<n2; idx+=1024) T[idx]=Tm[idx];
    __syncthreads();
  }
  for (int idx=threadIdx.x; idx<n2; idx+=1024){ Dd[l*961+idx]=T[idx]; Df[l*961+idx]=(float)T[idx]; }
}

// ---------------- quadrature weights + phase tables ----------------
__global__ void k_qw(float* qw30, float* qw16, float* qw10, float2* ph32, float2* ph20, float2* ph60){
  int t=threadIdx.x;
  if (t<60){
    double beta=M_PI*(2*t+1)/120.0, s=0.0;
    for (int j=0;j<30;j++) s += sin((double)(2*t+1)*(2*j+1)*M_PI/120.0)/(double)(2*j+1);
    qw30[t]=(float)((2.0/30.0)*sin(beta)*s);
    double a=2.0*M_PI*t/60.0; ph60[t]=make_float2((float)cos(a),(float)sin(a));
  }
  if (t<32){
    double beta=M_PI*(2*t+1)/64.0, s=0.0;
    for (int j=0;j<16;j++) s += sin((double)(2*t+1)*(2*j+1)*M_PI/64.0)/(double)(2*j+1);
    qw16[t]=(float)((2.0/16.0)*sin(beta)*s);
    double a=2.0*M_PI*t/32.0; ph32[t]=make_float2((float)cos(a),(float)sin(a));
  }
  if (t<20){
    double beta=M_PI*(2*t+1)/40.0, s=0.0;
    for (int j=0;j<10;j++) s += sin((double)(2*t+1)*(2*j+1)*M_PI/40.0)/(double)(2*j+1);
    qw10[t]=(float)((2.0/10.0)*sin(beta)*s);
    double a=2.0*M_PI*t/20.0; ph20[t]=make_float2((float)cos(a),(float)sin(a));
  }
}

// ---------------- beta-grid Wigner tables from Delta ----------------
__global__ void k_tables(const double* Dd, const float* qw30, const float* qw16, const float* qw10,
                         float* wd_s2, float* dif16, float* wd16, float* dif10){
  int bid=blockIdx.x;
  __shared__ double cc[32], ss[32];
  int l,k,mode; double beta;
  if (bid<960){ mode=0; l=bid/60; k=bid%60; beta=M_PI*(2*k+1)/120.0; }
  else if (bid<1472){ mode=1; int q=bid-960; l=q/32; k=q%32; beta=M_PI*(2*k+1)/64.0; }
  else { mode=2; int q=bid-1472; l=q/20; k=q%20; beta=M_PI*(2*k+1)/40.0; }
  int n=2*l+1;
  for (int kk=threadIdx.x; kk<=l; kk+=256){ cc[kk]=cos(kk*beta); ss[kk]=sin(kk*beta); }
  __syncthreads();
  const double* D = Dd + l*961;
  if (mode==0){
    for (int mm=threadIdx.x; mm<n; mm+=256){
      int m=mm-l; int p=((m)%4+4)%4; double s=0.0;
      for (int kk=-l; kk<=l; ++kk){
        int ak = kk<0?-kk:kk;
        double c=cc[ak], sn=(kk<0)?-ss[ak]:ss[ak];
        double f=(p==0)?c:(p==1)?sn:(p==2)?-c:-sn;
        s += D[(kk+l)*n+mm]*D[(kk+l)*n+l]*f;
      }
      wd_s2[(l*60+k)*31+mm] = (float)(s*(double)qw30[k]*(2.0*M_PI/60.0));
    }
  } else if (mode==1){
    for (int idx=threadIdx.x; idx<n*n; idx+=256){
      int mm=idx/n, nn=idx-mm*n; int m=mm-l, nb=nn-l;
      int p=((m-nb)%4+4)%4; double s=0.0;
      for (int kk=-l; kk<=l; ++kk){
        int ak = kk<0?-kk:kk;
        double c=cc[ak], sn=(kk<0)?-ss[ak]:ss[ak];
        double f=(p==0)?c:(p==1)?sn:(p==2)?-c:-sn;
        s += D[(kk+l)*n+mm]*D[(kk+l)*n+nn]*f;
      }
      dif16[(size_t)(l*32+k)*961+idx] = (float)((2*l+1)*s);
      if (l<10) wd16[(size_t)(l*32+k)*361+idx] = (float)(s*(double)qw16[k]*(2.0*M_PI/32.0)*(2.0*M_PI/32.0));
    }
  } else {
    for (int idx=threadIdx.x; idx<n*n; idx+=256){
      int mm=idx/n, nn=idx-mm*n; int m=mm-l, nb=nn-l;
      int p=((m-nb)%4+4)%4; double s=0.0;
      for (int kk=-l; kk<=l; ++kk){
        int ak = kk<0?-kk:kk;
        double c=cc[ak], sn=(kk<0)?-ss[ak]:ss[ak];
        double f=(p==0)?c:(p==1)?sn:(p==2)?-c:-sn;
        s += D[(kk+l)*n+mm]*D[(kk+l)*n+nn]*f;
      }
      dif10[(size_t)(l*20+k)*361+idx] = (float)((2*l+1)*s);
    }
  }
}

// ---------------- project point cloud to S2 grid (max-scatter) ----------------
__global__ void k_project(const float* x, float* img){
  int tid = blockIdx.x*256+threadIdx.x;
  if (tid>=8192) return;
  int b=tid>>10, n=tid&1023;
  float px=x[(b*3+0)*1024+n], py=x[(b*3+1)*1024+n], pz=x[(b*3+2)*1024+n];
  float r = sqrtf(px*px+py*py+pz*pz);
  float rc = fmaxf(r, 1e-8f);
  float ct = fminf(1.f, fmaxf(-1.f, pz/rc));
  float beta = acosf(ct);
  float alpha = atan2f(py, px);
  const float TWO_PI = 6.283185307179586f;
  alpha = fmodf(alpha, TWO_PI); if (alpha<0.f) alpha += TWO_PI;
  int bi = (int)(beta/3.14159265358979323846f*60.f); bi = min(59, max(0, bi));
  int ai = (int)(alpha/TWO_PI*60.f);                 ai = min(59, max(0, ai));
  atomicMax((int*)&img[(b*60+bi)*60+ai], __float_as_int(r));
}

// ---------------- S2 FFT stage a: alpha-DFT per (b,k) -> Gg[b,k,16] ----------------
__global__ void k_s2a(const float* __restrict__ img, const float2* __restrict__ ph60, float2* __restrict__ Gg){
  int bid=blockIdx.x; int b=bid/60, k=bid-60*b;
  __shared__ float im[60];
  int t=threadIdx.x;
  if (t<60) im[t]=img[(b*60+k)*60+t];
  __syncthreads();
  if (t<16){
    float sr=0.f, si=0.f;
    for (int a=0;a<60;a++){ float v=im[a]; float2 p=ph60[(t*a)%60]; sr+=v*p.x; si-=v*p.y; }
    Gg[(b*60+k)*16+t]=make_float2(sr,si);
  }
}

// ---------------- S2 FFT stage b: Gg -> X[b, l^2+mm] ----------------
__global__ void k_s2b(const float2* __restrict__ Gg, const float* __restrict__ wd_s2, float2* __restrict__ X){
  int b=blockIdx.x;
  __shared__ float2 G[960];
  for (int i=threadIdx.x;i<960;i+=256) G[i]=Gg[b*960+i];
  __syncthreads();
  int off=threadIdx.x; // exactly 256 outputs
  int l=0; while((l+1)*(l+1)<=off) l++;
  int mm=off-l*l; int m=mm-l; int am = m<0?-m:m;
  float xr=0.f, xi=0.f;
  for (int k=0;k<60;k++){
    float w=wd_s2[(l*60+k)*31+mm];
    float2 g=G[(k<<4)+am];
    float gi = (m<0)? -g.y : g.y;
    xr += w*g.x; xi += w*gi;
  }
  X[b*256+off]=make_float2(xr,xi);
}

// ---------------- S2 RFT: w_s2 -> YC[f*256+off] = conj(Y^l[f,mm]) ----------------
__global__ void k_yc(const float* w_s2, const float* Df, const float2* ph60, float2* YC){
  int f=blockIdx.x; int t=threadIdx.x; // 64 threads
  __shared__ float wv[60];
  __shared__ float2 W[16];
  for (int p=t;p<60;p+=64) wv[p]=w_s2[f*60+p];
  __syncthreads();
  if (t<16){
    float sr=0.f, si=0.f;
    for (int p=0;p<60;p++){ float2 ph=ph60[(t*p)%60]; sr+=wv[p]*ph.x; si-=wv[p]*ph.y; }
    W[t]=make_float2(sr/60.f, si/60.f);
  }
  __syncthreads();
  for (int off=t; off<256; off+=64){
    int l=0; while((l+1)*(l+1)<=off) l++;
    int mm=off-l*l; int m=mm-l; int am=m<0?-m:m;
    float dh=Df[l*961 + mm*(2*l+1) + l];
    float2 wm=W[am];
    float wi = (m>=0)? -wm.y : wm.y;   // conj(What[m_signed])
    YC[f*256+off]=make_float2(dh*wm.x, dh*wi);
  }
}

// ---------------- u compact (ns>=0), load-balanced: l>=8 blocks split ns-range ----------------
__global__ void k_u(const float2* X, const float* dif16, const float2* ph32g, float2* u){
  int bid=blockIdx.x;
  int l, k, ns0, ns1;
  if (bid < 256){ l = bid>>5; k = bid&31; ns0=0; ns1=l+1; }
  else {
    int q=bid-256; l = 8 + (q>>6); int half=(q>>5)&1; k=q&31;
    int mid=(l+2)>>1;  // ceil((l+1)/2)
    ns0 = half? mid : 0; ns1 = half? (l+1) : mid;
  }
  int n=2*l+1;
  __shared__ float d[961];
  __shared__ float2 Xs[8][31];
  __shared__ float2 ph[32];
  int t=threadIdx.x;
  if (t<32) ph[t]=ph32g[t];
  for (int i=t;i<n*n;i+=256) d[i]=dif16[(size_t)(l*32+k)*961+i];
  if (t<8*n){ int b=t/n, mm=t-b*n; Xs[b][mm]=X[b*256+l*l+mm]; }
  __syncthreads();
  int b=t>>5, a=t&31;
  int base=((b*32+k)*32+a)*136 + c_T[l];
  for (int ns=ns0; ns<ns1; ++ns){
    float ar=0.f, ai=0.f;
    int nn = ns + l;
    for (int mm=0; mm<n; ++mm){
      float2 x=Xs[b][mm];
      float2 p=ph[((mm-l)*a)&31];
      float pr=x.x*p.x-x.y*p.y, pi=x.x*p.y+x.y*p.x;
      float dv=d[mm*n+nn];
      ar += dv*pr; ai += dv*pi;
    }
    u[base+ns]=make_float2(ar,ai);
  }
}

// ---------------- big inverse transform v4 (R12-proven): R7 GEMM + transposed-h coalesced store + fused BN
// h stored TRANSPOSED: h[bc][k][g*32+a]. k_g is the only consumer.
#define KH_F 8
__global__ __launch_bounds__(256) void k_h(const float2* __restrict__ u, const float2* __restrict__ YC,
                                           const float2* __restrict__ ph32g, float* __restrict__ h,
                                           double2* __restrict__ part){
  int bid=blockIdx.x;
  int fg = bid % 13; int rem = bid/13; int k = rem & 31; int b = rem >> 5;
  int f0 = fg*KH_F; int F_act = (f0+KH_F<=100)? KH_F : (100-f0);

  __shared__ float usr[136*33], usi[136*33];   // [c][a] pad 33
  __shared__ float2 ysc[KH_F*136];             // [fi][c]
  __shared__ float vr[KH_F*32*17], vi[KH_F*32*17]; // [fi][a][ns] pad 17
  __shared__ float2 ph[32];
  int t=threadIdx.x;
  if (t<32) ph[t]=ph32g[t];

  // stage A: load u transposed [c][a], Y compact
  {
    const float2* ub = u + (size_t)((b*32+k)*32)*136;
    for (int i=t; i<32*136; i+=256){
      int a=i/136, c=i-a*136;
      float2 U=ub[i];
      usr[c*33+a]=U.x; usi[c*33+a]=U.y;
    }
  }
  for (int i=t; i<KH_F*136; i+=256){
    int fi=i/136, c=i-fi*136;
    float2 y=make_float2(0.f,0.f);
    if (fi<F_act){
      int l=l_from_T(c); int ns=c-c_T[l];
      y=YC[(size_t)(f0+fi)*256 + l*l+l+ns];
    }
    ysc[i]=y;
  }
  __syncthreads();

  // stage B: register-tiled GEMM, 256 jobs = ns(16) x ftile(2) x atile(8); acc 4f x 4a complex
  {
    int ns = t>>4; int sub = t&15; int ft = sub>>3; int at = sub&7;
    int a0 = at*4;
    float ar[16], ai[16];
    #pragma unroll
    for (int q=0;q<16;q++){ ar[q]=0.f; ai[q]=0.f; }
    for (int l=ns; l<16; ++l){
      int c = c_T[l]+ns;
      float2 y0=ysc[(ft*4+0)*136+c];
      float2 y1=ysc[(ft*4+1)*136+c];
      float2 y2=ysc[(ft*4+2)*136+c];
      float2 y3=ysc[(ft*4+3)*136+c];
      float ur0=usr[c*33+a0+0], ur1=usr[c*33+a0+1], ur2=usr[c*33+a0+2], ur3=usr[c*33+a0+3];
      float ui0=usi[c*33+a0+0], ui1=usi[c*33+a0+1], ui2=usi[c*33+a0+2], ui3=usi[c*33+a0+3];
      #define CM(j,Y,i_,URi,UIi) \
        ar[(j)*4+(i_)] += (Y).x*URi - (Y).y*UIi; \
        ai[(j)*4+(i_)] += (Y).x*UIi + (Y).y*URi;
      CM(0,y0,0,ur0,ui0) CM(0,y0,1,ur1,ui1) CM(0,y0,2,ur2,ui2) CM(0,y0,3,ur3,ui3)
      CM(1,y1,0,ur0,ui0) CM(1,y1,1,ur1,ui1) CM(1,y1,2,ur2,ui2) CM(1,y1,3,ur3,ui3)
      CM(2,y2,0,ur0,ui0) CM(2,y2,1,ur1,ui1) CM(2,y2,2,ur2,ui2) CM(2,y2,3,ur3,ui3)
      CM(3,y3,0,ur0,ui0) CM(3,y3,1,ur1,ui1) CM(3,y3,2,ur2,ui2) CM(3,y3,3,ur3,ui3)
      #undef CM
    }
    #pragma unroll
    for (int j=0;j<4;j++){
      #pragma unroll
      for (int i=0;i<4;i++){
        int fi=ft*4+j, a=a0+i;
        vr[(fi*32+a)*17+ns]=ar[j*4+i];
        vi[(fi*32+a)*17+ns]=ai[j*4+i];
      }
    }
  }
  __syncthreads();

  // stage C: gamma-DFT (g-fold) -> direct transposed coalesced store; fused BN partials
  {
    int fi=t>>5, a=t&31;
    float xr[16], xi[16];
    #pragma unroll
    for (int ns=0;ns<16;ns++){ xr[ns]=vr[(fi*32+a)*17+ns]; xi[ns]=vi[(fi*32+a)*17+ns]; }
    float vr0 = xr[0];
    bool wr = (fi<F_act);
    float* hp = h + ((size_t)(b*100+f0+fi)*32 + k)*1024 + a;
    double s=0.0, q=0.0;
    #pragma unroll
    for (int g=0; g<16; ++g){
      float se=0.f, so=0.f;
      #pragma unroll
      for (int ns=0; ns<16; ++ns){
        float2 p=ph[(ns*g)&31];
        float term = xr[ns]*p.x - xi[ns]*p.y;
        if (ns & 1) so += term; else se += term;
      }
      float hg  = 2.f*(se+so) - vr0;
      float hg16= 2.f*(se-so) - vr0;
      if (wr){ hp[g*32]=hg; hp[(g+16)*32]=hg16; }
      double d1=(double)hg, d2=(double)hg16;
      s += d1+d2; q += d1*d1+d2*d2;
    }
    for (int d=16; d>0; d>>=1){ s += __shfl_down(s, d, 32); q += __shfl_down(q, d, 32); }
    if (a==0 && fi<F_act){
      atomicAdd(&part[b*100+f0+fi].x, s);
      atomicAdd(&part[b*100+f0+fi].y, q);
    }
  }
}

// ---------------- BN stats, two-stage ----------------
__global__ void k_bn1(const float* __restrict__ x, int per, double2* __restrict__ partial){
  int bf=blockIdx.x; int t=threadIdx.x;
  const float4* p4=(const float4*)(x + (size_t)bf*per);
  int n4=per>>2;
  double s=0.0, q=0.0;
  for (int i=t;i<n4;i+=256){
    float4 v=p4[i];
    s += (double)v.x+(double)v.y+(double)v.z+(double)v.w;
    q += (double)v.x*v.x+(double)v.y*v.y+(double)v.z*v.z+(double)v.w*v.w;
  }
  __shared__ double rs[256], rq[256];
  rs[t]=s; rq[t]=q; __syncthreads();
  for (int w=128;w>0;w>>=1){ if(t<w){rs[t]+=rs[t+w]; rq[t]+=rq[t+w];} __syncthreads(); }
  if (t==0) partial[bf]=make_double2(rs[0],rq[0]);
}
__global__ void k_bn2(const double2* __restrict__ partial, int per, const float* g, const float* bb,
                      float* scale, float* shift){
  int f=blockIdx.x*64+threadIdx.x;
  if (f>=100) return;
  double s=0.0, q=0.0;
  for (int b=0;b<8;b++){ double2 v=partial[b*100+f]; s+=v.x; q+=v.y; }
  double cnt=8.0*(double)per;
  double mu=s/cnt, var=q/cnt-mu*mu;
  double sc=(double)g[f]/sqrt(var+1e-5);
  scale[f]=(float)sc; shift[f]=(float)((double)bb[f]-mu*sc);
}

// ---------------- k_g: per (b,c,k): BN+ReLU + alpha-DFT + gamma-DFT -> G[bc,k,190]
// h is TRANSPOSED [g*32+a]; LDS y padded [g*33+a].
__global__ __launch_bounds__(64) void k_g(const float* __restrict__ h, const float* __restrict__ scale,
                                          const float* __restrict__ shift, const float2* __restrict__ ph32g,
                                          float2* __restrict__ G){
  int bid=blockIdx.x; int k=bid&31; int bc=bid>>5; int c=bc%100;
  __shared__ float y[32*33];
  __shared__ float tsr[10*33], tsi[10*33];
  __shared__ float2 ph[32];
  int t=threadIdx.x;
  if (t<32) ph[t]=ph32g[t];
  float sc=scale[c], sh=shift[c];
  const float* hb = h + (size_t)bc*32768 + k*1024;
  for (int i=t;i<1024;i+=64){ int g=i>>5, a=i&31; y[g*33+a]=fmaxf(hb[i]*sc+sh, 0.f); }
  __syncthreads();
  for (int i=t;i<320;i+=64){
    int m=i>>5, g=i&31;
    float sr=0.f, si=0.f;
    for (int a=0;a<32;a++){ float v=y[g*33+a]; float2 p=ph[(m*a)&31]; sr+=v*p.x; si-=v*p.y; }
    tsr[m*33+g]=sr; tsi[m*33+g]=si;
  }
  __syncthreads();
  float2* Gp = G + (size_t)(bc*32+k)*190;
  for (int i=t;i<190;i+=64){
    int m=i/19, n9=i-m*19; int ns=n9-9;
    float gr=0.f, gi=0.f;
    for (int g=0;g<32;g++){
      float tr=tsr[m*33+g], ti=tsi[m*33+g];
      float2 p=ph[(ns*g)&31];
      gr += tr*p.x + ti*p.y;
      gi += ti*p.x - tr*p.y;
    }
    Gp[i]=make_float2(gr,gi);
  }
}

// ---------------- k_x2 (half rows m>=0): X2h[bc, offH(l)+m*n+kk] = sum_k wd16[l,k,(m+l)*n+kk] * G[bc,k,j]
__global__ void k_x2(const float2* __restrict__ G, const float* __restrict__ wd16, float2* __restrict__ X2){
  int tid=blockIdx.x*256+threadIdx.x;
  if (tid>=800*715) return;
  int bc=tid/715, i=tid-bc*715;
  int l=l_from_offH(i); int rem=i-c_offH[l]; int n=2*l+1;
  int m=rem/n, kk2=rem-m*n; int ng=kk2-l;   // m>=0 always
  int j = m*19+(ng+9);
  const float2* Gp = G + (size_t)bc*32*190 + j;
  const float*  wp = wd16 + (size_t)l*32*361 + (m+l)*n + kk2;
  float ar=0.f, ai=0.f;
  #pragma unroll 4
  for (int k=0;k<32;k++){
    float2 gv=Gp[(size_t)k*190];
    float  wv=wp[(size_t)k*361];
    ar += wv*gv.x; ai += wv*gv.y;
  }
  X2[tid]=make_float2(ar, ai);
}

// ---------------- What2[m,i,o] ----------------
__global__ void k_wh2(const float* w_so3, const float2* ph32g, float2* WH2){
  int tid=blockIdx.x*256+threadIdx.x;
  if (tid>=10000) return;
  int i=tid/100, o=tid-i*100;
  float wv[32];
  for (int p=0;p<32;p++) wv[p]=w_so3[(i*100+o)*32+p];
  for (int m=0;m<10;m++){
    float sr=0.f, si=0.f;
    for (int p=0;p<32;p++){ float2 ph=ph32g[(m*p)&31]; sr+=wv[p]*ph.x; si-=wv[p]*ph.y; }
    WH2[((size_t)m*100+i)*100+o]=make_float2(sr/32.f, si/32.f);
  }
}

// ---------------- A (half rows): A[bi, offH(l)+m*n+nn] = sum_kk X2h[bi, row m][kk] * Delta^l[nn,kk]
__global__ void k_A(const float2* __restrict__ X2, const float* __restrict__ Df, float2* __restrict__ A){
  int tid = blockIdx.x*256 + threadIdx.x;
  if (tid >= 800*715) return;
  int bi = tid/715, off = tid - bi*715;
  int l = l_from_offH(off); int rem = off - c_offH[l]; int n = 2*l+1;
  int m = rem/n, nn = rem - m*n;
  const float2* Xp = X2 + (size_t)bi*715 + c_offH[l] + m*n;
  const float* Dp = Df + l*961 + nn*n;
  float ar=0.f, ai=0.f;
  for (int kk=0; kk<n; ++kk){
    float2 x = Xp[kk]; float dv = Dp[kk];
    ar += x.x*dv; ai += x.y*dv;
  }
  A[tid] = make_float2(ar, ai);
}

// ---------------- Z2 (half rows): Z2h[b,o, offH(l)+m*n+nn] = sum_i A[b,i, m,nn] * conj(What2[i,o,nsig])
__global__ void k_z2(const float2* A, const float2* WH2, float2* Z2){
  int bid=blockIdx.x; int b=bid&7; int r=bid>>3;
  int l=l_from_sq(r); int nn=r-l*l; int n=2*l+1; int ns=nn-l;
  int nrow=l+1;
  __shared__ float2 As[100*10];
  int t=threadIdx.x;
  for (int idx=t; idx<100*nrow; idx+=256){
    int i=idx/nrow, m=idx-i*nrow;
    As[idx]=A[(size_t)(b*100+i)*715 + c_offH[l] + m*n + nn];
  }
  __syncthreads();
  int mabs = ns<0?-ns:ns;
  const float2* Wp = WH2 + (size_t)mabs*10000;
  float sgn = (ns>=0)? -1.f : 1.f;
  for (int idx=t; idx<100*nrow; idx+=256){
    int o=idx/nrow, m=idx-o*nrow;
    float zr=0.f, zi=0.f;
    for (int i=0;i<100;i++){
      float2 a=As[i*nrow+m];
      float2 w=Wp[i*100+o]; float wr=w.x, wi=sgn*w.y;
      zr += a.x*wr - a.y*wi;
      zi += a.x*wi + a.y*wr;
    }
    Z2[(size_t)(b*100+o)*715 + c_offH[l] + m*n + nn]=make_float2(zr,zi);
  }
}

// ---------------- fused SO3 IFFT at b=10 v2: one block per (bf,k), Hermitian half, no table staging
// Reads Z2 in HALF layout (rows ms>=0 only).
__global__ __launch_bounds__(128) void k_ifft10(const float2* __restrict__ Z2, const float* __restrict__ dif10,
                                                const float2* __restrict__ ph20g, float* __restrict__ h2){
  int bid=blockIdx.x; int bf=bid/20, k=bid-20*bf;
  __shared__ float2 M[190];    // [ms 0..9][n9 0..18]
  __shared__ float2 T[200];    // [ms 0..9][g 0..19]
  __shared__ float2 ph[20];
  int t=threadIdx.x;
  if (t<20) ph[t]=ph20g[t];
  const float2* Zp = Z2 + (size_t)bf*715;
  __syncthreads();
  for (int i=t;i<190;i+=128){
    int ms=i/19, n9=i-ms*19; int nsg=n9-9;
    int a2=nsg<0?-nsg:nsg; int l0 = ms>a2?ms:a2;
    float mr=0.f, mi=0.f;
    for (int l=l0;l<10;l++){
      int n=2*l+1;
      float dv=dif10[(size_t)(l*20+k)*361 + (ms+l)*n+(nsg+l)];
      float2 z=Zp[c_offH[l] + ms*n + (nsg+l)];
      mr += dv*z.x; mi += dv*z.y;
    }
    M[i]=make_float2(mr,mi);
  }
  __syncthreads();
  for (int i=t;i<200;i+=128){
    int ms=i/20, g=i-20*ms;
    const float2* Mp=M+ms*19;
    int idx=(11*g)%20;
    float tr=0.f, ti=0.f;
    #pragma unroll
    for (int n9=0;n9<19;n9++){
      float2 mv=Mp[n9]; float2 p=ph[idx];
      tr += mv.x*p.x - mv.y*p.y;
      ti += mv.x*p.y + mv.y*p.x;
      idx += g; if (idx>=20) idx-=20;
    }
    T[i]=make_float2(tr,ti);
  }
  __syncthreads();
  float* hp = h2 + (size_t)bf*8000 + k*400;
  for (int i=t;i<400;i+=128){
    int a=i/20, g=i-20*a;
    float acc = T[g].x;
    int cur=a;
    #pragma unroll
    for (int ms=1; ms<10; ++ms){
      float2 tv=T[ms*20+g]; float2 p=ph[cur];
      acc += 2.f*(tv.x*p.x - tv.y*p.y);
      cur += a; if (cur>=20) cur-=20;
    }
    hp[i]=acc;
  }
}

// ---------------- BN2+ReLU + SO3 integrate -> feat ----------------
__global__ void k_integrate(const float* h2, const float* scale, const float* shift, const float* qw10, float* feat){
  int bf=blockIdx.x; int f=bf%100; int t=threadIdx.x;
  float sc=scale[f], sh=shift[f];
  const float* p=h2+(size_t)bf*8000;
  float s=0.f;
  for (int i=t;i<8000;i+=256){
    float v=fmaxf(p[i]*sc+sh, 0.f);
    s += v*qw10[i/400];
  }
  __shared__ float r[256];
  r[t]=s; __syncthreads();
  for (int w=128;w>0;w>>=1){ if(t<w) r[t]+=r[t+w]; __syncthreads(); }
  if (t==0){
    float c=(float)((2.0*M_PI/20.0)*(2.0*M_PI/20.0));
    feat[bf]=r[0]*c;
  }
}

// ---------------- final linear ----------------
__global__ void k_logits(const float* feat, const float* lw, const float* lb, float* out){
  int t=blockIdx.x*64+threadIdx.x;
  if (t>=320) return;
  int b=t/40, c=t-40*b;
  float s=lb[c];
  for (int f=0;f<100;f++) s += feat[b*100+f]*lw[f*40+c];
  out[t]=s;
}

extern "C" void kernel_launch(void* const* d_in, const int* in_sizes, int n_in,
                              void* d_out, int out_size, void* d_ws, size_t ws_size,
                              hipStream_t stream){
  (void)in_sizes; (void)n_in; (void)out_size; (void)ws_size;
  const float* x    = (const float*)d_in[0];
  const float* w_s2 = (const float*)d_in[1];
  const float* bn1g = (const float*)d_in[3];
  const float* bn1b = (const float*)d_in[4];
  const float* w_so3= (const float*)d_in[5];
  const float* bn2g = (const float*)d_in[7];
  const float* bn2b = (const float*)d_in[8];
  const float* linw = (const float*)d_in[9];
  const float* linb = (const float*)d_in[10];
  float* out = (float*)d_out;

  char* base=(char*)d_ws; size_t off=0;
  auto alloc=[&](size_t bytes)->void*{ void* p=base+off; off=(off+bytes+255)&~(size_t)255; return p; };
  double* Dd   = (double*)alloc((size_t)16*961*8);
  float*  Df   = (float*) alloc((size_t)16*961*4);
  float*  qw30 = (float*) alloc(256);
  float*  qw16 = (float*) alloc(256);
  float*  qw10 = (float*) alloc(256);
  float2* ph60 = (float2*)alloc(512);
  float2* ph32 = (float2*)alloc(256);
  float2* ph20 = (float2*)alloc(256);
  float*  wd_s2= (float*) alloc((size_t)16*60*31*4);
  float*  dif16= (float*) alloc((size_t)16*32*961*4);
  float*  wd16 = (float*) alloc((size_t)10*32*361*4);
  float*  dif10= (float*) alloc((size_t)10*20*361*4);
  float*  img  = (float*) alloc((size_t)8*3600*4);
  float2* Gg   = (float2*)alloc((size_t)8*960*8);
  float2* X    = (float2*)alloc((size_t)8*256*8);
  float2* YC   = (float2*)alloc((size_t)100*256*8);
  float2* u    = (float2*)alloc((size_t)8*32*32*136*8);
  float*  h    = (float*) alloc((size_t)8*100*32768*4);
  float*  sc1  = (float*) alloc(512);
  float*  sh1  = (float*) alloc(512);
  float2* Gbuf = (float2*)alloc((size_t)800*32*190*8);
  float2* X2   = (float2*)alloc((size_t)800*715*8);
  float2* WH2  = (float2*)alloc((size_t)10*100*100*8);
  float2* A    = (float2*)alloc((size_t)800*715*8);
  float2* Z2   = (float2*)alloc((size_t)800*715*8);
  float*  h2   = (float*) alloc((size_t)8*100*8000*4);
  float*  sc2  = (float*) alloc(512);
  float*  sh2  = (float*) alloc(512);
  float*  feat = (float*) alloc(4096);
  double2* part= (double2*)alloc((size_t)800*16);

  k_delta<<<16, 1024, 0, stream>>>(Dd, Df);
  k_qw<<<1, 64, 0, stream>>>(qw30, qw16, qw10, ph32, ph20, ph60);
  k_tables<<<1672, 256, 0, stream>>>(Dd, qw30, qw16, qw10, wd_s2, dif16, wd16, dif10);
  hipMemsetAsync(img, 0, (size_t)8*3600*4, stream);
  hipMemsetAsync(part, 0, (size_t)800*16, stream);
  k_project<<<32, 256, 0, stream>>>(x, img);
  k_s2a<<<480, 64, 0, stream>>>(img, ph60, Gg);
  k_s2b<<<8, 256, 0, stream>>>(Gg, wd_s2, X);
  k_yc<<<100, 64, 0, stream>>>(w_s2, Df, ph60, YC);
  k_u<<<768, 256, 0, stream>>>(X, dif16, ph32, u);
  k_h<<<8*32*13, 256, 0, stream>>>(u, YC, ph32, h, part);
  k_bn2<<<2, 64, 0, stream>>>(part, 32768, bn1g, bn1b, sc1, sh1);
  k_g<<<800*32, 64, 0, stream>>>(h, sc1, sh1, ph32, Gbuf);
  k_x2<<<(800*715+255)/256, 256, 0, stream>>>(Gbuf, wd16, X2);
  k_wh2<<<40, 256, 0, stream>>>(w_so3, ph32, WH2);
  k_A<<<(800*715+255)/256, 256, 0, stream>>>(X2, Df, A);
  k_z2<<<800, 256, 0, stream>>>(A, WH2, Z2);
  k_ifft10<<<16000, 128, 0, stream>>>(Z2, dif10, ph20, h2);
  k_bn1<<<800, 256, 0, stream>>>(h2, 8000, part);
  k_bn2<<<2, 64, 0, stream>>>(part, 8000, bn2g, bn2b, sc2, sh2);
  k_integrate<<<800, 256, 0, stream>>>(h2, sc2, sh2, qw10, feat);
  k_logits<<<5, 64, 0, stream>>>(feat, linw, linb, out);
}